// Round 7
// baseline (32.435 us; speedup 1.0000x reference)
//
#include <hip/hip_runtime.h>
#include <math.h>

// LDAWordGenerator: z[b,v] = logsumexp_t(log_theta[b,t] + log_phi[t,v])
// Factored: z = mu_v + log( sum_t Ea[b,t] * Ew[t,v] )
//   Ea[b][t] = exp(log_theta[b,t] - g_t),  g_t = max_b log_theta[b,t]
//   Ew[t][v] = exp(w[t,v] + c_t - mu_v),   c_t = g_t - lse_w[t]
//   mu_v = max_t (w[t,v] + c_t)  -> dominant term has Ew=1, Ea >= e^-spread: safe.
// Matmul over t via bf16 MFMA. B=128, T=128, V=32000.

constexpr int B = 128;
constexpr int T = 128;
constexpr int V = 32000;
constexpr int VC = 64;            // V-columns per k_main block
constexpr int KPARTS = 4;
constexpr int PART = V / KPARTS;  // 8000

// ws layout (32-bit words): EaPacked[8192] | pm[512] | ps[512] | gt[128]
constexpr int WS_EA = 0;          // linear layout: word[b*64 + tp] = {t=2tp, t=2tp+1}
constexpr int WS_PM = 8192;
constexpr int WS_PS = WS_PM + T * KPARTS;
constexpr int WS_GT = WS_PS + T * KPARTS;

typedef __attribute__((ext_vector_type(8))) short bf16x8;
typedef __attribute__((ext_vector_type(4))) float f32x4;
typedef __attribute__((ext_vector_type(4))) unsigned u32x4;

__device__ inline unsigned short f2bf(float f) {
    union { float f; unsigned u; } x; x.f = f;
    unsigned u = x.u + 0x7fff + ((x.u >> 16) & 1);   // round-to-nearest-even
    return (unsigned short)(u >> 16);
}

// ---------------- KA: block 0 = prep (chunked, 17KB LDS); blocks 1..512 = lse_w partials ----
__global__ __launch_bounds__(256) void k_stage1(const float* __restrict__ inp,
                                                const float* __restrict__ w,
                                                float* __restrict__ pm,
                                                float* __restrict__ ps,
                                                float* __restrict__ gt_out,
                                                unsigned* __restrict__ Ea) {
    __shared__ float si[32][129];    // 16.5 KiB chunk (also aliased by lse blocks)
    __shared__ float lse_b[B];
    __shared__ float gts[T];
    const int tid = threadIdx.x;

    if (blockIdx.x != 0) {
        // ---- lse_w partial over one quarter-row of w (2-pass) ----
        const int bid = blockIdx.x - 1;
        const int t = bid >> 2;
        const int part = bid & 3;
        const float4* row = (const float4*)(w + (size_t)t * V + (size_t)part * PART);

        float* sm = &si[0][0];
        float* ss = &si[4][0];

        // pass 1: block max (pure fmax)
        float m = -INFINITY;
        for (int i = tid; i < PART / 4; i += 256) {
            float4 x4 = row[i];
            m = fmaxf(fmaxf(m, fmaxf(x4.x, x4.y)), fmaxf(x4.z, x4.w));
        }
        sm[tid] = m;
        __syncthreads();
        for (int off = 128; off > 0; off >>= 1) {
            if (tid < off) sm[tid] = fmaxf(sm[tid], sm[tid + off]);
            __syncthreads();
        }
        const float M = sm[0];

        // pass 2: sum exp(x - M), rows L2-warm
        float s = 0.f;
        for (int i = tid; i < PART / 4; i += 256) {
            float4 x4 = row[i];
            s += __expf(x4.x - M) + __expf(x4.y - M) + __expf(x4.z - M) + __expf(x4.w - M);
        }
        ss[tid] = s;
        __syncthreads();
        for (int off = 128; off > 0; off >>= 1) {
            if (tid < off) ss[tid] += ss[tid + off];
            __syncthreads();
        }
        if (tid == 0) { pm[bid] = M; ps[bid] = ss[0]; }
        return;
    }

    // ---- prep block: 4 chunks of 32 rows ----
    const int row8 = tid >> 3;   // row within chunk (0..31)
    const int sub = tid & 7;     // 8 threads per row

    // pass 1: lse_in per row + g_t partials
    float greg = -INFINITY;      // for tid < 128: g over all b of (log_theta)
    for (int c = 0; c < 4; ++c) {
        // stage chunk: 1024 float4, 4 per thread
        #pragma unroll
        for (int k = 0; k < 4; ++k) {
            int i4 = tid + k * 256;
            float4 x = ((const float4*)inp)[c * 1024 + i4];
            int r = i4 >> 5, col = (i4 & 31) * 4;
            float* dst = &si[r][col];
            dst[0] = x.x; dst[1] = x.y; dst[2] = x.z; dst[3] = x.w;
        }
        __syncthreads();

        // row lse: 8-thread group per row, shfl reduce
        {
            const float* row = si[row8];
            float m = -INFINITY;
            #pragma unroll
            for (int j = 0; j < 16; ++j) m = fmaxf(m, row[sub * 16 + j]);
            #pragma unroll
            for (int d = 1; d < 8; d <<= 1) m = fmaxf(m, __shfl_xor(m, d, 64));
            float s = 0.f;
            #pragma unroll
            for (int j = 0; j < 16; ++j) s += __expf(row[sub * 16 + j] - m);
            #pragma unroll
            for (int d = 1; d < 8; d <<= 1) s += __shfl_xor(s, d, 64);
            if (sub == 0) lse_b[c * 32 + row8] = m + logf(s);
        }
        __syncthreads();

        // g partial over this chunk's rows
        if (tid < T) {
            #pragma unroll 8
            for (int r = 0; r < 32; ++r)
                greg = fmaxf(greg, si[r][tid] - lse_b[c * 32 + r]);
        }
        __syncthreads();
    }
    if (tid < T) { gts[tid] = greg; gt_out[tid] = greg; }
    __syncthreads();

    // pass 2: re-stage chunks (L2-warm), pack Ea bf16 pairs -> global (linear layout)
    for (int c = 0; c < 4; ++c) {
        #pragma unroll
        for (int k = 0; k < 4; ++k) {
            int i4 = tid + k * 256;
            float4 x = ((const float4*)inp)[c * 1024 + i4];
            int r = i4 >> 5, col = (i4 & 31) * 4;
            float* dst = &si[r][col];
            dst[0] = x.x; dst[1] = x.y; dst[2] = x.z; dst[3] = x.w;
        }
        __syncthreads();

        const int b = c * 32 + row8;
        const float li = lse_b[b];
        #pragma unroll
        for (int k = 0; k < 8; ++k) {
            int tp = sub * 8 + k;
            float e0 = __expf(si[row8][2 * tp]     - li - gts[2 * tp]);
            float e1 = __expf(si[row8][2 * tp + 1] - li - gts[2 * tp + 1]);
            Ea[b * 64 + tp] = (unsigned)f2bf(e0) | ((unsigned)f2bf(e1) << 16);
        }
        __syncthreads();
    }
}

// ---------------- KB: register-staged w; A-fragments straight from global (L1-hot) ----------------
__global__ __launch_bounds__(256) void k_main(const float* __restrict__ w,
                                              const float* __restrict__ pm,
                                              const float* __restrict__ ps,
                                              const float* __restrict__ gt,
                                              const unsigned* __restrict__ Ea_g,
                                              float* __restrict__ out) {
    __shared__ unsigned EwL[VC * 64];   // 16 KiB, swizzled [v][tp]; aliased as mu-partial scratch
    __shared__ float cs[T];
    __shared__ float mu[VC];

    float* pmT = (float*)EwL;           // [VC][17] mu partials, dead before EwL written

    const int tid = threadIdx.x;
    const int vbase = blockIdx.x * VC;
    const int v4 = tid & 15;            // owns v = v4*4 .. v4*4+3
    const int tq = tid >> 4;            // owns t = tq*8 .. tq*8+7

    // issue the block's whole w slab into registers: 8 x float4 per thread
    f32x4 wr[8];
    {
        const float* wp = w + (size_t)(tq * 8) * V + vbase + v4 * 4;
        #pragma unroll
        for (int i = 0; i < 8; ++i)
            wr[i] = *(const f32x4*)(wp + (size_t)i * V);
    }

    if (tid < T) {   // c_t = g_t - lse_w[t]
        const int t = tid;
        float M = pm[t * KPARTS];
        #pragma unroll
        for (int p = 1; p < KPARTS; ++p) M = fmaxf(M, pm[t * KPARTS + p]);
        float S = 0.f;
        #pragma unroll
        for (int p = 0; p < KPARTS; ++p) S += ps[t * KPARTS + p] * __expf(pm[t * KPARTS + p] - M);
        cs[t] = gt[t] - (M + logf(S));
    }
    __syncthreads();   // cs ready

    // mu partials from registers
    {
        float p0 = -INFINITY, p1 = -INFINITY, p2 = -INFINITY, p3 = -INFINITY;
        #pragma unroll
        for (int i = 0; i < 8; ++i) {
            const float cc = cs[tq * 8 + i];
            p0 = fmaxf(p0, wr[i][0] + cc);
            p1 = fmaxf(p1, wr[i][1] + cc);
            p2 = fmaxf(p2, wr[i][2] + cc);
            p3 = fmaxf(p3, wr[i][3] + cc);
        }
        pmT[(v4 * 4 + 0) * 17 + tq] = p0;
        pmT[(v4 * 4 + 1) * 17 + tq] = p1;
        pmT[(v4 * 4 + 2) * 17 + tq] = p2;
        pmT[(v4 * 4 + 3) * 17 + tq] = p3;
    }
    __syncthreads();
    if (tid < VC) {
        float m = pmT[tid * 17];
        #pragma unroll
        for (int r = 1; r < 16; ++r) m = fmaxf(m, pmT[tid * 17 + r]);
        mu[tid] = m;
    }
    __syncthreads();   // pmT dead from here

    // Ew from registers: exp(w + c - mu), pack bf16 pairs, swizzled 16B writes
    {
        #pragma unroll
        for (int c = 0; c < 4; ++c) {
            const int v = v4 * 4 + c;
            const float m_ = mu[v];
            unsigned pk[4];
            #pragma unroll
            for (int p2 = 0; p2 < 4; ++p2) {
                float e0 = __expf(wr[2 * p2][c]     + cs[tq * 8 + 2 * p2]     - m_);
                float e1 = __expf(wr[2 * p2 + 1][c] + cs[tq * 8 + 2 * p2 + 1] - m_);
                pk[p2] = (unsigned)f2bf(e0) | ((unsigned)f2bf(e1) << 16);
            }
            *(u32x4*)&EwL[v * 64 + ((tq ^ (v & 15)) << 2)] = (u32x4){pk[0], pk[1], pk[2], pk[3]};
        }
    }
    __syncthreads();

    // MFMA: C[b][v] = sum_t Ea[b][t]*Ew^T[v][t]. 4 waves, each 64b x 32v.
    // A-fragments read directly from global (32KB, L1-resident, linear layout).
    const int lane = tid & 63;
    const int wave = tid >> 6;
    const int wb = (wave >> 1) * 64;
    const int wv = (wave & 1) * 32;
    const int r = lane & 15;
    const int g = lane >> 4;

    f32x4 acc[4][2];
    #pragma unroll
    for (int m = 0; m < 4; ++m)
        #pragma unroll
        for (int n = 0; n < 2; ++n) acc[m][n] = (f32x4){0.f, 0.f, 0.f, 0.f};

    #pragma unroll
    for (int kk = 0; kk < 4; ++kk) {
        const int grp = kk * 4 + g;
        bf16x8 af[4], bfr[2];
        #pragma unroll
        for (int m = 0; m < 4; ++m) {
            int bb = wb + m * 16 + r;
            af[m] = *(const bf16x8*)((const char*)Ea_g + bb * 256 + grp * 16);
        }
        #pragma unroll
        for (int n = 0; n < 2; ++n) {
            int vv = wv + n * 16 + r;
            bfr[n] = *(const bf16x8*)((const char*)EwL + vv * 256 + ((grp ^ (vv & 15)) << 4));
        }
        #pragma unroll
        for (int m = 0; m < 4; ++m)
            #pragma unroll
            for (int n = 0; n < 2; ++n)
                acc[m][n] = __builtin_amdgcn_mfma_f32_16x16x32_bf16(af[m], bfr[n], acc[m][n], 0, 0, 0);
    }

    // epilogue: z = mu_v + log(P). C layout: col=lane&15, row=g*4+j.
    #pragma unroll
    for (int m = 0; m < 4; ++m) {
        int bb = wb + m * 16 + g * 4;
        #pragma unroll
        for (int n = 0; n < 2; ++n) {
            float muv = mu[wv + n * 16 + r];
            size_t col = (size_t)(vbase + wv + n * 16 + r);
            #pragma unroll
            for (int j = 0; j < 4; ++j)
                out[(size_t)(bb + j) * V + col] = muv + __logf(acc[m][n][j]);
        }
    }
}

extern "C" void kernel_launch(void* const* d_in, const int* in_sizes, int n_in,
                              void* d_out, int out_size, void* d_ws, size_t ws_size,
                              hipStream_t stream) {
    const float* inp = (const float*)d_in[0];  // (B, T) f32
    const float* w   = (const float*)d_in[1];  // (T, V) f32
    float* out = (float*)d_out;                // (B, V) f32
    unsigned* ws = (unsigned*)d_ws;

    unsigned* Ea = ws + WS_EA;
    float* pm = (float*)(ws + WS_PM);
    float* ps = (float*)(ws + WS_PS);
    float* gt = (float*)(ws + WS_GT);

    k_stage1<<<dim3(T * KPARTS + 1), dim3(256), 0, stream>>>(inp, w, pm, ps, gt, Ea);
    k_main<<<dim3(V / VC), dim3(256), 0, stream>>>(w, pm, ps, gt, Ea, out);
}

// Round 8
// 29.007 us; speedup vs baseline: 1.1182x; 1.1182x over previous
//
#include <hip/hip_runtime.h>
#include <math.h>

// LDAWordGenerator: z[b,v] = logsumexp_t(log_theta[b,t] + log_phi[t,v])
// Factored: z = mu_v + log( sum_t Ea[b,t] * Ew[t,v] )
//   Ea[b][t] = exp(log_theta[b,t] - g_t),  g_t = max_b log_theta[b,t]
//   Ew[t][v] = exp(w[t,v] + c_t - mu_v),   c_t = g_t - lse_w[t]
//   mu_v = max_t (w[t,v] + c_t)  -> dominant term has Ew=1, Ea >= e^-spread: safe.
// Matmul over t via bf16 MFMA. B=128, T=128, V=32000.

constexpr int B = 128;
constexpr int T = 128;
constexpr int V = 32000;
constexpr int VC = 64;            // V-columns per k_main block
constexpr int KPARTS = 4;
constexpr int PART = V / KPARTS;  // 8000

// ws layout (32-bit words): EaPacked[8192] | pm[512] | ps[512] | gt[128]
constexpr int WS_EA = 0;          // swizzled packed bf16 pairs
constexpr int WS_PM = 8192;
constexpr int WS_PS = WS_PM + T * KPARTS;
constexpr int WS_GT = WS_PS + T * KPARTS;

typedef __attribute__((ext_vector_type(8))) short bf16x8;
typedef __attribute__((ext_vector_type(4))) float f32x4;
typedef __attribute__((ext_vector_type(4))) unsigned u32x4;

__device__ inline unsigned short f2bf(float f) {
    union { float f; unsigned u; } x; x.f = f;
    unsigned u = x.u + 0x7fff + ((x.u >> 16) & 1);   // round-to-nearest-even
    return (unsigned short)(u >> 16);
}

// Swizzled word index within a 64-word (256B) row: 16B-group (tp>>2) XOR (row&15).
__device__ inline int swz_word(int row, int tp) {
    return (((tp >> 2) ^ (row & 15)) << 2) | (tp & 3);
}

// ---------------- KA: block 0 = prep; blocks 1..512 = lse_w partials (2-pass) ----
__global__ __launch_bounds__(256) void k_stage1(const float* __restrict__ inp,
                                                const float* __restrict__ w,
                                                float* __restrict__ pm,
                                                float* __restrict__ ps,
                                                float* __restrict__ gt_out,
                                                unsigned* __restrict__ Ea) {
    __shared__ float sh[B * (T + 1)];   // prep: si[b][t] at sh[b*129+t], lse_in at col 128
    __shared__ float gts[T];
    const int tid = threadIdx.x;

    if (blockIdx.x != 0) {
        const int bid = blockIdx.x - 1;
        const int t = bid >> 2;
        const int part = bid & 3;
        const float4* row = (const float4*)(w + (size_t)t * V + (size_t)part * PART);

        // pass 1: block max (pure fmax)
        float m = -INFINITY;
        #pragma unroll 4
        for (int i = tid; i < PART / 4; i += 256) {
            float4 x4 = row[i];
            m = fmaxf(fmaxf(m, fmaxf(x4.x, x4.y)), fmaxf(x4.z, x4.w));
        }
        float* sm = sh;
        sm[tid] = m;
        __syncthreads();
        for (int off = 128; off > 0; off >>= 1) {
            if (tid < off) sm[tid] = fmaxf(sm[tid], sm[tid + off]);
            __syncthreads();
        }
        const float M = sm[0];

        // pass 2: sum of exp(x - M), rows L2-warm
        float s = 0.f;
        #pragma unroll 4
        for (int i = tid; i < PART / 4; i += 256) {
            float4 x4 = row[i];
            s += __expf(x4.x - M) + __expf(x4.y - M) + __expf(x4.z - M) + __expf(x4.w - M);
        }
        float* ss = sh + 256;
        ss[tid] = s;
        __syncthreads();
        for (int off = 128; off > 0; off >>= 1) {
            if (tid < off) ss[tid] += ss[tid + off];
            __syncthreads();
        }
        if (tid == 0) { pm[bid] = M; ps[bid] = ss[0]; }
        return;
    }

    // ---- prep block ----
    #pragma unroll
    for (int k = 0; k < 16; ++k) {
        int i4 = tid + k * 256;
        float4 x = ((const float4*)inp)[i4];
        int r = i4 >> 5, c = (i4 & 31) * 4;
        float* dst = &sh[r * 129 + c];
        dst[0] = x.x; dst[1] = x.y; dst[2] = x.z; dst[3] = x.w;
    }
    __syncthreads();

    if (tid < B) {   // lse_in[b] -> pad column 128
        const int b = tid;
        const float* row = &sh[b * 129];
        float m = -INFINITY;
        for (int t = 0; t < T; ++t) m = fmaxf(m, row[t]);
        float s = 0.f;
        for (int t = 0; t < T; ++t) s += __expf(row[t] - m);
        sh[b * 129 + 128] = m + logf(s);
    }
    __syncthreads();

    if (tid < T) {   // g_t = max_b(inp[b][t] - lse_in[b])
        const int t = tid;
        float g = -INFINITY;
        for (int b = 0; b < B; ++b) g = fmaxf(g, sh[b * 129 + t] - sh[b * 129 + 128]);
        gts[t] = g;
        gt_out[t] = g;
    }
    __syncthreads();

    if (tid < B) {   // pack Ea bf16 pairs in place into row b (swizzled)
        const int b = tid;
        const float li = sh[b * 129 + 128];
        unsigned pk[64];
        #pragma unroll
        for (int tp = 0; tp < 64; ++tp) {
            float e0 = __expf(sh[b * 129 + 2 * tp]     - li - gts[2 * tp]);
            float e1 = __expf(sh[b * 129 + 2 * tp + 1] - li - gts[2 * tp + 1]);
            pk[tp] = (unsigned)f2bf(e0) | ((unsigned)f2bf(e1) << 16);
        }
        unsigned* row = (unsigned*)&sh[b * 129];
        #pragma unroll
        for (int tp = 0; tp < 64; ++tp) row[swz_word(b, tp)] = pk[tp];
    }
    __syncthreads();

    #pragma unroll
    for (int k = 0; k < 32; ++k) {   // coalesced copy-out
        int d = tid + k * 256;
        int b = d >> 6, wsw = d & 63;
        Ea[d] = ((unsigned*)&sh[b * 129])[wsw];
    }
}

// ---------------- KB: register-staged w, LDS Ea/Ew, MFMA, epilogue ----------------
__global__ __launch_bounds__(256) void k_main(const float* __restrict__ w,
                                              const float* __restrict__ pm,
                                              const float* __restrict__ ps,
                                              const float* __restrict__ gt,
                                              const unsigned* __restrict__ Ea_g,
                                              float* __restrict__ out) {
    __shared__ unsigned EaL[B * 64];    // 32 KiB, swizzled [b][tp]
    __shared__ unsigned EwL[VC * 64];   // 16 KiB, swizzled [v][tp]
    __shared__ float cs[T];
    __shared__ float mu[VC];
    __shared__ float pmT[VC][17];       // mu partials, conflict-free pad

    const int tid = threadIdx.x;
    const int vbase = blockIdx.x * VC;
    const int v4 = tid & 15;            // owns v = v4*4 .. v4*4+3
    const int tq = tid >> 4;            // owns t = tq*8 .. tq*8+7

    // issue the block's whole w slab into registers: 8 x float4 per thread
    f32x4 wr[8];
    {
        const float* wp = w + (size_t)(tq * 8) * V + vbase + v4 * 4;
        #pragma unroll
        for (int i = 0; i < 8; ++i)
            wr[i] = *(const f32x4*)(wp + (size_t)i * V);
    }

    if (tid < T) {   // c_t = g_t - lse_w[t]
        const int t = tid;
        float M = pm[t * KPARTS];
        #pragma unroll
        for (int p = 1; p < KPARTS; ++p) M = fmaxf(M, pm[t * KPARTS + p]);
        float S = 0.f;
        #pragma unroll
        for (int p = 0; p < KPARTS; ++p) S += ps[t * KPARTS + p] * __expf(pm[t * KPARTS + p] - M);
        cs[t] = gt[t] - (M + logf(S));
    }

    // stage Ea (pre-swizzled in ws): linear 32 KiB copy
    {
        const float4* src = (const float4*)Ea_g;
        float4* dst = (float4*)EaL;
        #pragma unroll
        for (int k = 0; k < 8; ++k) dst[tid + k * 256] = src[tid + k * 256];
    }
    __syncthreads();   // cs ready

    // mu partials from registers: p[c] = max_i (wr[i][c] + cs[tq*8+i])
    {
        float p0 = -INFINITY, p1 = -INFINITY, p2 = -INFINITY, p3 = -INFINITY;
        #pragma unroll
        for (int i = 0; i < 8; ++i) {
            const float cc = cs[tq * 8 + i];
            p0 = fmaxf(p0, wr[i][0] + cc);
            p1 = fmaxf(p1, wr[i][1] + cc);
            p2 = fmaxf(p2, wr[i][2] + cc);
            p3 = fmaxf(p3, wr[i][3] + cc);
        }
        pmT[v4 * 4 + 0][tq] = p0;
        pmT[v4 * 4 + 1][tq] = p1;
        pmT[v4 * 4 + 2][tq] = p2;
        pmT[v4 * 4 + 3][tq] = p3;
    }
    __syncthreads();
    if (tid < VC) {
        float m = pmT[tid][0];
        #pragma unroll
        for (int r = 1; r < 16; ++r) m = fmaxf(m, pmT[tid][r]);
        mu[tid] = m;
    }
    __syncthreads();

    // Ew from registers: exp(w + c - mu), pack bf16 pairs, swizzled 16B writes
    {
        #pragma unroll
        for (int c = 0; c < 4; ++c) {
            const int v = v4 * 4 + c;
            const float m_ = mu[v];
            unsigned pk[4];
            #pragma unroll
            for (int p2 = 0; p2 < 4; ++p2) {
                float e0 = __expf(wr[2 * p2][c]     + cs[tq * 8 + 2 * p2]     - m_);
                float e1 = __expf(wr[2 * p2 + 1][c] + cs[tq * 8 + 2 * p2 + 1] - m_);
                pk[p2] = (unsigned)f2bf(e0) | ((unsigned)f2bf(e1) << 16);
            }
            *(u32x4*)&EwL[v * 64 + ((tq ^ (v & 15)) << 2)] = (u32x4){pk[0], pk[1], pk[2], pk[3]};
        }
    }
    __syncthreads();

    // MFMA: C[b][v] = sum_t Ea[b][t]*Ew^T[v][t]. 4 waves, each 64b x 32v.
    const int lane = tid & 63;
    const int wave = tid >> 6;
    const int wb = (wave >> 1) * 64;
    const int wv = (wave & 1) * 32;
    const int r = lane & 15;
    const int g = lane >> 4;

    f32x4 acc[4][2];
    #pragma unroll
    for (int m = 0; m < 4; ++m)
        #pragma unroll
        for (int n = 0; n < 2; ++n) acc[m][n] = (f32x4){0.f, 0.f, 0.f, 0.f};

    #pragma unroll
    for (int kk = 0; kk < 4; ++kk) {
        const int grp = kk * 4 + g;
        bf16x8 af[4], bfr[2];
        #pragma unroll
        for (int m = 0; m < 4; ++m) {
            int bb = wb + m * 16 + r;
            af[m] = *(const bf16x8*)((const char*)EaL + bb * 256 + ((grp ^ (bb & 15)) << 4));
        }
        #pragma unroll
        for (int n = 0; n < 2; ++n) {
            int vv = wv + n * 16 + r;
            bfr[n] = *(const bf16x8*)((const char*)EwL + vv * 256 + ((grp ^ (vv & 15)) << 4));
        }
        #pragma unroll
        for (int m = 0; m < 4; ++m)
            #pragma unroll
            for (int n = 0; n < 2; ++n)
                acc[m][n] = __builtin_amdgcn_mfma_f32_16x16x32_bf16(af[m], bfr[n], acc[m][n], 0, 0, 0);
    }

    // epilogue: z = mu_v + log(P). C layout: col=lane&15, row=g*4+j.
    // nontemporal: out is write-once, keep it out of L2.
    #pragma unroll
    for (int m = 0; m < 4; ++m) {
        int bb = wb + m * 16 + g * 4;
        #pragma unroll
        for (int n = 0; n < 2; ++n) {
            float muv = mu[wv + n * 16 + r];
            size_t col = (size_t)(vbase + wv + n * 16 + r);
            #pragma unroll
            for (int j = 0; j < 4; ++j)
                __builtin_nontemporal_store(muv + __logf(acc[m][n][j]),
                                            out + (size_t)(bb + j) * V + col);
        }
    }
}

extern "C" void kernel_launch(void* const* d_in, const int* in_sizes, int n_in,
                              void* d_out, int out_size, void* d_ws, size_t ws_size,
                              hipStream_t stream) {
    const float* inp = (const float*)d_in[0];  // (B, T) f32
    const float* w   = (const float*)d_in[1];  // (T, V) f32
    float* out = (float*)d_out;                // (B, V) f32
    unsigned* ws = (unsigned*)d_ws;

    unsigned* Ea = ws + WS_EA;
    float* pm = (float*)(ws + WS_PM);
    float* ps = (float*)(ws + WS_PS);
    float* gt = (float*)(ws + WS_GT);

    k_stage1<<<dim3(T * KPARTS + 1), dim3(256), 0, stream>>>(inp, w, pm, ps, gt, Ea);
    k_main<<<dim3(V / VC), dim3(256), 0, stream>>>(w, pm, ps, gt, Ea, out);
}

// Round 9
// 28.634 us; speedup vs baseline: 1.1327x; 1.0130x over previous
//
#include <hip/hip_runtime.h>
#include <math.h>

// LDAWordGenerator: z[b,v] = logsumexp_t(log_theta[b,t] + log_phi[t,v])
// Factored: z = mu_v + log( sum_t Ea[b,t] * Ew[t,v] )
//   Ea[b][t] = exp(log_theta[b,t] - g_t),  g_t = max_b log_theta[b,t]
//   Ew[t][v] = exp(w[t,v] + c_t - mu_v),   c_t = g_t - lse_w[t]
//   mu_v = max_t (w[t,v] + c_t)  -> dominant term has Ew=1, Ea >= e^-spread: safe.
// Matmul over t via bf16 MFMA. B=128, T=128, V=32000.

constexpr int B = 128;
constexpr int T = 128;
constexpr int V = 32000;
constexpr int VC = 64;            // V-columns per k_main block
constexpr int KPARTS = 4;
constexpr int PART = V / KPARTS;  // 8000 floats = 2000 float4

// ws layout (32-bit words): EaPacked[8192] | pm[512] | ps[512] | gt[128]
constexpr int WS_EA = 0;          // swizzled packed bf16 pairs
constexpr int WS_PM = 8192;
constexpr int WS_PS = WS_PM + T * KPARTS;
constexpr int WS_GT = WS_PS + T * KPARTS;

typedef __attribute__((ext_vector_type(8))) short bf16x8;
typedef __attribute__((ext_vector_type(4))) float f32x4;
typedef __attribute__((ext_vector_type(4))) unsigned u32x4;

__device__ inline unsigned short f2bf(float f) {
    union { float f; unsigned u; } x; x.f = f;
    unsigned u = x.u + 0x7fff + ((x.u >> 16) & 1);   // round-to-nearest-even
    return (unsigned short)(u >> 16);
}

// Swizzled word index within a 64-word (256B) row: 16B-group (tp>>2) XOR (row&15).
__device__ inline int swz_word(int row, int tp) {
    return (((tp >> 2) ^ (row & 15)) << 2) | (tp & 3);
}

// ---------------- KA: 512 blocks. block 0 = prep; blocks 1..511 = lse_w partials
//                  (register-resident single load; block 1 takes the orphan partial) ----
__global__ __launch_bounds__(256) void k_stage1(const float* __restrict__ inp,
                                                const float* __restrict__ w,
                                                float* __restrict__ pm,
                                                float* __restrict__ ps,
                                                float* __restrict__ gt_out,
                                                unsigned* __restrict__ Ea) {
    __shared__ float sh[B * (T + 1)];   // prep: si[b][t] at sh[b*129+t], lse_in at col 128
    __shared__ float gts[T];
    const int tid = threadIdx.x;
    const int bid = blockIdx.x;

    if (bid != 0) {
        float* sm = sh;          // [256]
        float* ss = sh + 256;    // [256]
        const int nparts = (bid == 1) ? 2 : 1;
        for (int pi = 0; pi < nparts; ++pi) {
            const int p = (pi == 0) ? (bid - 1) : (T * KPARTS - 1);
            const int t = p >> 2;
            const int part = p & 3;
            const float4* row = (const float4*)(w + (size_t)t * V + (size_t)part * PART);

            // single pass: load 8 float4 into registers (predicated tail)
            f32x4 xr[8];
            #pragma unroll
            for (int k = 0; k < 8; ++k) {
                int idx = tid + k * 256;
                if (idx < PART / 4) xr[k] = *(const f32x4*)&row[idx];
                else xr[k] = (f32x4){-INFINITY, -INFINITY, -INFINITY, -INFINITY};
            }

            // max from registers
            float m = -INFINITY;
            #pragma unroll
            for (int k = 0; k < 8; ++k)
                m = fmaxf(fmaxf(fmaxf(m, xr[k][0]), fmaxf(xr[k][1], xr[k][2])), xr[k][3]);
            sm[tid] = m;
            __syncthreads();
            for (int off = 128; off > 0; off >>= 1) {
                if (tid < off) sm[tid] = fmaxf(sm[tid], sm[tid + off]);
                __syncthreads();
            }
            const float M = sm[0];

            // exp-sum from registers (pad lanes give exp(-inf)=0)
            float s = 0.f;
            #pragma unroll
            for (int k = 0; k < 8; ++k)
                s += __expf(xr[k][0] - M) + __expf(xr[k][1] - M) +
                     __expf(xr[k][2] - M) + __expf(xr[k][3] - M);
            ss[tid] = s;
            __syncthreads();
            for (int off = 128; off > 0; off >>= 1) {
                if (tid < off) ss[tid] += ss[tid + off];
                __syncthreads();
            }
            if (tid == 0) { pm[p] = M; ps[p] = ss[0]; }
            __syncthreads();   // LDS reuse across pi
        }
        return;
    }

    // ---- prep block (block 0 only) ----
    #pragma unroll
    for (int k = 0; k < 16; ++k) {
        int i4 = tid + k * 256;
        float4 x = ((const float4*)inp)[i4];
        int r = i4 >> 5, c = (i4 & 31) * 4;
        float* dst = &sh[r * 129 + c];
        dst[0] = x.x; dst[1] = x.y; dst[2] = x.z; dst[3] = x.w;
    }
    __syncthreads();

    if (tid < B) {   // lse_in[b] -> pad column 128
        const int b = tid;
        const float* row = &sh[b * 129];
        float m = -INFINITY;
        for (int t = 0; t < T; ++t) m = fmaxf(m, row[t]);
        float s = 0.f;
        for (int t = 0; t < T; ++t) s += __expf(row[t] - m);
        sh[b * 129 + 128] = m + logf(s);
    }
    __syncthreads();

    if (tid < T) {   // g_t = max_b(inp[b][t] - lse_in[b])
        const int t = tid;
        float g = -INFINITY;
        #pragma unroll 4
        for (int b = 0; b < B; ++b) g = fmaxf(g, sh[b * 129 + t] - sh[b * 129 + 128]);
        gts[t] = g;
        gt_out[t] = g;
    }
    __syncthreads();

    if (tid < B) {   // pack Ea bf16 pairs in place into row b (swizzled)
        const int b = tid;
        const float li = sh[b * 129 + 128];
        unsigned pk[64];
        #pragma unroll
        for (int tp = 0; tp < 64; ++tp) {
            float e0 = __expf(sh[b * 129 + 2 * tp]     - li - gts[2 * tp]);
            float e1 = __expf(sh[b * 129 + 2 * tp + 1] - li - gts[2 * tp + 1]);
            pk[tp] = (unsigned)f2bf(e0) | ((unsigned)f2bf(e1) << 16);
        }
        unsigned* row = (unsigned*)&sh[b * 129];
        #pragma unroll
        for (int tp = 0; tp < 64; ++tp) row[swz_word(b, tp)] = pk[tp];
    }
    __syncthreads();

    #pragma unroll
    for (int k = 0; k < 32; ++k) {   // coalesced copy-out
        int d = tid + k * 256;
        int b = d >> 6, wsw = d & 63;
        Ea[d] = ((unsigned*)&sh[b * 129])[wsw];
    }
}

// ---------------- KB: register-staged w, LDS Ea/Ew, MFMA, epilogue ----------------
__global__ __launch_bounds__(256) void k_main(const float* __restrict__ w,
                                              const float* __restrict__ pm,
                                              const float* __restrict__ ps,
                                              const float* __restrict__ gt,
                                              const unsigned* __restrict__ Ea_g,
                                              float* __restrict__ out) {
    __shared__ unsigned EaL[B * 64];    // 32 KiB, swizzled [b][tp]
    __shared__ unsigned EwL[VC * 64];   // 16 KiB, swizzled [v][tp]
    __shared__ float cs[T];
    __shared__ float mu[VC];
    __shared__ float pmT[VC][17];       // mu partials, conflict-free pad

    const int tid = threadIdx.x;
    const int vbase = blockIdx.x * VC;
    const int v4 = tid & 15;            // owns v = v4*4 .. v4*4+3
    const int tq = tid >> 4;            // owns t = tq*8 .. tq*8+7

    // issue the block's whole w slab into registers: 8 x float4 per thread
    f32x4 wr[8];
    {
        const float* wp = w + (size_t)(tq * 8) * V + vbase + v4 * 4;
        #pragma unroll
        for (int i = 0; i < 8; ++i)
            wr[i] = *(const f32x4*)(wp + (size_t)i * V);
    }

    if (tid < T) {   // c_t = g_t - lse_w[t]
        const int t = tid;
        float M = pm[t * KPARTS];
        #pragma unroll
        for (int p = 1; p < KPARTS; ++p) M = fmaxf(M, pm[t * KPARTS + p]);
        float S = 0.f;
        #pragma unroll
        for (int p = 0; p < KPARTS; ++p) S += ps[t * KPARTS + p] * __expf(pm[t * KPARTS + p] - M);
        cs[t] = gt[t] - (M + logf(S));
    }

    // stage Ea (pre-swizzled in ws): linear 32 KiB copy
    {
        const float4* src = (const float4*)Ea_g;
        float4* dst = (float4*)EaL;
        #pragma unroll
        for (int k = 0; k < 8; ++k) dst[tid + k * 256] = src[tid + k * 256];
    }
    __syncthreads();   // cs ready

    // mu partials from registers: p[c] = max_i (wr[i][c] + cs[tq*8+i])
    {
        float p0 = -INFINITY, p1 = -INFINITY, p2 = -INFINITY, p3 = -INFINITY;
        #pragma unroll
        for (int i = 0; i < 8; ++i) {
            const float cc = cs[tq * 8 + i];
            p0 = fmaxf(p0, wr[i][0] + cc);
            p1 = fmaxf(p1, wr[i][1] + cc);
            p2 = fmaxf(p2, wr[i][2] + cc);
            p3 = fmaxf(p3, wr[i][3] + cc);
        }
        pmT[v4 * 4 + 0][tq] = p0;
        pmT[v4 * 4 + 1][tq] = p1;
        pmT[v4 * 4 + 2][tq] = p2;
        pmT[v4 * 4 + 3][tq] = p3;
    }
    __syncthreads();
    if (tid < VC) {
        float m = pmT[tid][0];
        #pragma unroll
        for (int r = 1; r < 16; ++r) m = fmaxf(m, pmT[tid][r]);
        mu[tid] = m;
    }
    __syncthreads();

    // Ew from registers: exp(w + c - mu), pack bf16 pairs, swizzled 16B writes
    {
        #pragma unroll
        for (int c = 0; c < 4; ++c) {
            const int v = v4 * 4 + c;
            const float m_ = mu[v];
            unsigned pk[4];
            #pragma unroll
            for (int p2 = 0; p2 < 4; ++p2) {
                float e0 = __expf(wr[2 * p2][c]     + cs[tq * 8 + 2 * p2]     - m_);
                float e1 = __expf(wr[2 * p2 + 1][c] + cs[tq * 8 + 2 * p2 + 1] - m_);
                pk[p2] = (unsigned)f2bf(e0) | ((unsigned)f2bf(e1) << 16);
            }
            *(u32x4*)&EwL[v * 64 + ((tq ^ (v & 15)) << 2)] = (u32x4){pk[0], pk[1], pk[2], pk[3]};
        }
    }
    __syncthreads();

    // MFMA: C[b][v] = sum_t Ea[b][t]*Ew^T[v][t]. 4 waves, each 64b x 32v.
    const int lane = tid & 63;
    const int wave = tid >> 6;
    const int wb = (wave >> 1) * 64;
    const int wv = (wave & 1) * 32;
    const int r = lane & 15;
    const int g = lane >> 4;

    f32x4 acc[4][2];
    #pragma unroll
    for (int m = 0; m < 4; ++m)
        #pragma unroll
        for (int n = 0; n < 2; ++n) acc[m][n] = (f32x4){0.f, 0.f, 0.f, 0.f};

    #pragma unroll
    for (int kk = 0; kk < 4; ++kk) {
        const int grp = kk * 4 + g;
        bf16x8 af[4], bfr[2];
        #pragma unroll
        for (int m = 0; m < 4; ++m) {
            int bb = wb + m * 16 + r;
            af[m] = *(const bf16x8*)((const char*)EaL + bb * 256 + ((grp ^ (bb & 15)) << 4));
        }
        #pragma unroll
        for (int n = 0; n < 2; ++n) {
            int vv = wv + n * 16 + r;
            bfr[n] = *(const bf16x8*)((const char*)EwL + vv * 256 + ((grp ^ (vv & 15)) << 4));
        }
        #pragma unroll
        for (int m = 0; m < 4; ++m)
            #pragma unroll
            for (int n = 0; n < 2; ++n)
                acc[m][n] = __builtin_amdgcn_mfma_f32_16x16x32_bf16(af[m], bfr[n], acc[m][n], 0, 0, 0);
    }

    // epilogue: z = mu_v + log(P). C layout: col=lane&15, row=g*4+j.
    // nontemporal: out is write-once, keep it out of L2.
    #pragma unroll
    for (int m = 0; m < 4; ++m) {
        int bb = wb + m * 16 + g * 4;
        #pragma unroll
        for (int n = 0; n < 2; ++n) {
            float muv = mu[wv + n * 16 + r];
            size_t col = (size_t)(vbase + wv + n * 16 + r);
            #pragma unroll
            for (int j = 0; j < 4; ++j)
                __builtin_nontemporal_store(muv + __logf(acc[m][n][j]),
                                            out + (size_t)(bb + j) * V + col);
        }
    }
}

extern "C" void kernel_launch(void* const* d_in, const int* in_sizes, int n_in,
                              void* d_out, int out_size, void* d_ws, size_t ws_size,
                              hipStream_t stream) {
    const float* inp = (const float*)d_in[0];  // (B, T) f32
    const float* w   = (const float*)d_in[1];  // (T, V) f32
    float* out = (float*)d_out;                // (B, V) f32
    unsigned* ws = (unsigned*)d_ws;

    unsigned* Ea = ws + WS_EA;
    float* pm = (float*)(ws + WS_PM);
    float* ps = (float*)(ws + WS_PS);
    float* gt = (float*)(ws + WS_GT);

    k_stage1<<<dim3(512), dim3(256), 0, stream>>>(inp, w, pm, ps, gt, Ea);
    k_main<<<dim3(V / VC), dim3(256), 0, stream>>>(w, pm, ps, gt, Ea, out);
}